// Round 7
// baseline (96.088 us; speedup 1.0000x reference)
//
#include <hip/hip_runtime.h>

// SememeEmbeddingKNN, 2-kernel decomposition.
//   emb      [V=50257, H=1024] f32   (206 MB -> L3-resident, L2-thin)
//   word_ids [L=256, W=16]     i32
//   sem_ids  [L=256, W=16, S=32] i32
//   out      [L, H] f32
//
// R6 -> R7:
//  A: (1) merged-butterfly wave reduction: 10 ds-shuffles/wave instead of 48
//     (each level pairs values via cndmask-select + one shfl_xor, halving the
//     live-value count while reducing one lane bit). Final: lane 8m holds
//     dist[m] fully reduced -> 8-lane coalesced scalar store.
//     (2) nontemporal sememe-row loads (zero L1/L2 reuse; keep word rows
//     resident instead).
//  BC unchanged: select (strict '>', earliest index on ties = jax top_k)
//     fused with float4 gather/accumulate. No atomics, no memset.

#define HDIM 1024
#define SNUM 32
#define WNUM 16
#define KNN  3

typedef float f32x4 __attribute__((ext_vector_type(4)));

// ---------------- Phase A: partial distances (wave per b,octet,quarter) ----
__global__ __launch_bounds__(256) void knn_dist_kernel(
    const float* __restrict__ emb,
    const int*   __restrict__ word_ids,
    const int*   __restrict__ sem_ids,
    float*       __restrict__ dist_part,   // [4][nj]
    int nj)
{
    const int wave = threadIdx.x >> 6;     // octet 0..3
    const int lane = threadIdx.x & 63;
    const int blk  = blockIdx.x;           // b*4 + quarter
    const int b    = blk >> 2;
    const int quarter = blk & 3;

    __shared__ float s_w[256];

    const int wid = word_ids[b];
    s_w[threadIdx.x] = emb[(size_t)wid * HDIM + quarter * 256 + threadIdx.x];

    const int base_s = b * SNUM + wave * 8;
    const int col    = quarter * 256 + 4 * lane;

    const int4 sa = *(const int4*)(sem_ids + base_s);
    const int4 sb = *(const int4*)(sem_ids + base_s + 4);

    __syncthreads();
    const float4 w = *(const float4*)(s_w + 4 * lane);

    const int sids[8] = {sa.x, sa.y, sa.z, sa.w, sb.x, sb.y, sb.z, sb.w};
    f32x4 sv[8];
    #pragma unroll
    for (int k = 0; k < 8; ++k)
        sv[k] = __builtin_nontemporal_load(
            (const f32x4*)(emb + (size_t)sids[k] * HDIM + col));

    float d[8];
    #pragma unroll
    for (int k = 0; k < 8; ++k) {
        const float dx = sv[k].x - w.x;
        const float dy = sv[k].y - w.y;
        const float dz = sv[k].z - w.z;
        const float dw = sv[k].w - w.w;
        d[k] = (dx * dx + dy * dy) + (dz * dz + dw * dw);
    }

    // Merged butterfly: value count halves as each lane-bit is reduced.
    // After L32: e[k] holds d[k] (lanes<32) / d[k+4] (lanes>=32), bit5 summed.
    const bool hi32 = (lane & 32) != 0;
    float e[4];
    #pragma unroll
    for (int k = 0; k < 4; ++k) {
        const float x = hi32 ? d[k + 4] : d[k];
        float       y = hi32 ? d[k]     : d[k + 4];
        y = __shfl_xor(y, 32, 64);
        e[k] = x + y;
    }
    // After L16: f[k] index = k + 2*bit4 + 4*bit5, bits{5,4} summed.
    const bool hi16 = (lane & 16) != 0;
    float f[2];
    #pragma unroll
    for (int k = 0; k < 2; ++k) {
        const float x = hi16 ? e[k + 2] : e[k];
        float       y = hi16 ? e[k]     : e[k + 2];
        y = __shfl_xor(y, 16, 64);
        f[k] = x + y;
    }
    // After L8: g index = bit3 + 2*bit4 + 4*bit5, bits{5,4,3} summed.
    const bool hi8 = (lane & 8) != 0;
    {
        const float x = hi8 ? f[1] : f[0];
        float       y = hi8 ? f[0] : f[1];
        y = __shfl_xor(y, 8, 64);
        f[0] = x + y;
    }
    // Remaining lane bits 2,1,0.
    f[0] += __shfl_xor(f[0], 4, 64);
    f[0] += __shfl_xor(f[0], 2, 64);
    f[0] += __shfl_xor(f[0], 1, 64);

    // Lane 8m holds dist[m] (m = bit3 + 2*bit4 + 4*bit5 of lane = lane>>3).
    if ((lane & 7) == 0)
        dist_part[(size_t)quarter * nj + base_s + (lane >> 3)] = f[0];
}

// ------------- Phase BC: select (top-3) + gather/accumulate, fused --------
__global__ __launch_bounds__(256) void knn_outsel_kernel(
    const float* __restrict__ emb,
    const float* __restrict__ dist_part,   // [4][nj]
    const int*   __restrict__ word_ids,
    const int*   __restrict__ sem_ids,
    float*       __restrict__ out,
    int nj)
{
    const int l = blockIdx.x;
    const int t = threadIdx.x;

    __shared__ int s_ids[WNUM * 4];

    // Stage 1: threads 0..15 each select for one word.
    if (t < WNUM) {
        const int b = l * WNUM + t;
        float4 acc[8];
        #pragma unroll
        for (int i = 0; i < 8; ++i) acc[i] = make_float4(0.f, 0.f, 0.f, 0.f);
        #pragma unroll
        for (int q = 0; q < 4; ++q) {
            const float4* p = (const float4*)(dist_part + (size_t)q * nj + b * SNUM);
            #pragma unroll
            for (int i = 0; i < 8; ++i) {
                const float4 v = p[i];
                acc[i].x += v.x; acc[i].y += v.y; acc[i].z += v.z; acc[i].w += v.w;
            }
        }
        float dl[SNUM];
        #pragma unroll
        for (int i = 0; i < 8; ++i) {
            dl[4 * i + 0] = acc[i].x;
            dl[4 * i + 1] = acc[i].y;
            dl[4 * i + 2] = acc[i].z;
            dl[4 * i + 3] = acc[i].w;
        }
        // Top-3 descending; strict '>' keeps earliest index (= jax top_k).
        unsigned chosen = 0;
        #pragma unroll
        for (int k = 0; k < KNN; ++k) {
            float best = -1.0f;
            int   bi   = 0;
            #pragma unroll
            for (int s = 0; s < SNUM; ++s) {
                if (!((chosen >> s) & 1u) && dl[s] > best) { best = dl[s]; bi = s; }
            }
            chosen |= (1u << bi);
            s_ids[t * 4 + k] = sem_ids[b * SNUM + bi];
        }
        s_ids[t * 4 + 3] = word_ids[b];
    }
    __syncthreads();

    // Stage 2: all 256 threads gather float4 at h = 4t.
    const float third = 1.0f / 3.0f;
    float ax = 0.f, ay = 0.f, az = 0.f, aw = 0.f;
    #pragma unroll 4
    for (int w = 0; w < WNUM; ++w) {
        const float4 e0 = *(const float4*)(emb + (size_t)s_ids[w * 4 + 0] * HDIM + 4 * t);
        const float4 e1 = *(const float4*)(emb + (size_t)s_ids[w * 4 + 1] * HDIM + 4 * t);
        const float4 e2 = *(const float4*)(emb + (size_t)s_ids[w * 4 + 2] * HDIM + 4 * t);
        const float4 ew = *(const float4*)(emb + (size_t)s_ids[w * 4 + 3] * HDIM + 4 * t);
        ax += (e0.x + e1.x + e2.x) * third + ew.x;
        ay += (e0.y + e1.y + e2.y) * third + ew.y;
        az += (e0.z + e1.z + e2.z) * third + ew.z;
        aw += (e0.w + e1.w + e2.w) * third + ew.w;
    }
    const float scale = 0.5f / 16.0f;
    *(float4*)(out + (size_t)l * HDIM + 4 * t) =
        make_float4(ax * scale, ay * scale, az * scale, aw * scale);
}

extern "C" void kernel_launch(void* const* d_in, const int* in_sizes, int n_in,
                              void* d_out, int out_size, void* d_ws, size_t ws_size,
                              hipStream_t stream) {
    const float* emb  = (const float*)d_in[0];
    const int*   wids = (const int*)d_in[1];
    const int*   sids = (const int*)d_in[2];
    float*       out  = (float*)d_out;

    const int nb = in_sizes[1];          // L*W = 4096
    const int nj = in_sizes[2];          // L*W*S = 131072
    const int L  = out_size / HDIM;      // 256

    float* dist_part = (float*)d_ws;     // 4*nj floats (2 MB)

    knn_dist_kernel<<<dim3(nb * 4), dim3(256), 0, stream>>>(emb, wids, sids, dist_part, nj);
    knn_outsel_kernel<<<dim3(L), dim3(256), 0, stream>>>(emb, dist_part, wids, sids, out, nj);
}